// Round 3
// baseline (378.480 us; speedup 1.0000x reference)
//
#include <hip/hip_runtime.h>
#include <stdint.h>

typedef unsigned short u16;
typedef __bf16 bf16x8 __attribute__((ext_vector_type(8)));
typedef float f32x4 __attribute__((ext_vector_type(4)));

#define S_LEN 4096
#define D_MODEL 1024
#define NHEAD 16
#define HDIM 64

__device__ __forceinline__ u16 f2bf(float f) {
  unsigned u = __builtin_bit_cast(unsigned, f);
  u += 0x7fffu + ((u >> 16) & 1u);
  return (u16)(u >> 16);
}

// XOR swizzle of 16B units within a 128B (64 x bf16) row: unit ^= row&7
__device__ __forceinline__ int swz(int row, int col) {
  return (((col >> 3) ^ (row & 7)) << 3) | (col & 7);
}

__device__ __forceinline__ void gload16(const void* g, void* l) {
  auto gp = reinterpret_cast<__attribute__((address_space(1))) void*>(
      reinterpret_cast<uintptr_t>(g));
  auto lp = reinterpret_cast<__attribute__((address_space(3))) void*>(
      static_cast<unsigned>(reinterpret_cast<uintptr_t>(l)));
  __builtin_amdgcn_global_load_lds(gp, lp, 16, 0, 0);
}

// ---------------- fp32 -> bf16 elementwise ----------------
__global__ __launch_bounds__(256) void k_conv(const float* __restrict__ in,
                                              u16* __restrict__ out, int n) {
  int i = (blockIdx.x * 256 + threadIdx.x) * 4;
  if (i >= n) return;
  float4 v = *reinterpret_cast<const float4*>(in + i);
  ushort4 o = make_ushort4(f2bf(v.x), f2bf(v.y), f2bf(v.z), f2bf(v.w));
  *reinterpret_cast<ushort4*>(out + i) = o;
}

// ---------------- fp32 [R][C] -> bf16 [C][R] ----------------
__global__ __launch_bounds__(256) void k_transpose_conv(const float* __restrict__ in,
                                                        u16* __restrict__ out,
                                                        int R, int C) {
  __shared__ float tile[32][33];
  int c0 = blockIdx.x * 32, r0 = blockIdx.y * 32;
  int tx = threadIdx.x, ty = threadIdx.y;
#pragma unroll
  for (int j = 0; j < 4; ++j)
    tile[ty + j * 8][tx] = in[(size_t)(r0 + ty + j * 8) * C + c0 + tx];
  __syncthreads();
#pragma unroll
  for (int j = 0; j < 4; ++j)
    out[(size_t)(c0 + ty + j * 8) * R + r0 + tx] = f2bf(tile[tx][ty + j * 8]);
}

// ---------------- bf16 GEMM: C[M,N] = A[M,K] * Bt[N,K]^T + bias ----------------
// MODE 0: scatter into Q/K/Vt per-head bf16 layouts (with XOR swizzle)
// MODE 1: fp32 output, row-major
template <int MODE>
__global__ __launch_bounds__(256) void k_gemm(
    const u16* __restrict__ A, const u16* __restrict__ Bt,
    const float* __restrict__ bias, float* __restrict__ Cf,
    u16* __restrict__ Qd, u16* __restrict__ Kd, u16* __restrict__ Vtd,
    int M, int N, int K) {
  __shared__ __align__(16) u16 lds[2][2 * 128 * 32];
  const int tid = threadIdx.x;
  const int w = tid >> 6, lane = tid & 63;
  const int m0 = blockIdx.y * 128, n0 = blockIdx.x * 128;
  const u16* Atile = A + (size_t)m0 * K;
  const u16* Btile = Bt + (size_t)n0 * K;
  const int r = tid >> 2, c = (tid & 3) * 8;
  const int wm = (w >> 1) * 64, wn = (w & 1) * 64;

  f32x4 acc[4][4] = {};
  const int NT = K / 32;

  {  // stage tile 0
    const u16* ga = Atile + (size_t)r * K + c;
    const u16* gb = Btile + (size_t)r * K + c;
    u16* lb = lds[0];
    gload16(ga, lb + w * 512);
    gload16(ga + (size_t)64 * K, lb + 2048 + w * 512);
    gload16(gb, lb + 4096 + w * 512);
    gload16(gb + (size_t)64 * K, lb + 4096 + 2048 + w * 512);
  }
  int cur = 0;
  for (int t = 0; t < NT; ++t) {
    __syncthreads();
    if (t + 1 < NT) {
      const u16* ga = Atile + (size_t)r * K + (t + 1) * 32 + c;
      const u16* gb = Btile + (size_t)r * K + (t + 1) * 32 + c;
      u16* lb = lds[cur ^ 1];
      gload16(ga, lb + w * 512);
      gload16(ga + (size_t)64 * K, lb + 2048 + w * 512);
      gload16(gb, lb + 4096 + w * 512);
      gload16(gb + (size_t)64 * K, lb + 4096 + 2048 + w * 512);
    }
    const u16* lA = lds[cur];
    const u16* lB = lds[cur] + 4096;
    bf16x8 af[4], bfv[4];
#pragma unroll
    for (int mi = 0; mi < 4; ++mi)
      af[mi] = *reinterpret_cast<const bf16x8*>(
          lA + (wm + mi * 16 + (lane & 15)) * 32 + (lane >> 4) * 8);
#pragma unroll
    for (int ni = 0; ni < 4; ++ni)
      bfv[ni] = *reinterpret_cast<const bf16x8*>(
          lB + (wn + ni * 16 + (lane & 15)) * 32 + (lane >> 4) * 8);
#pragma unroll
    for (int mi = 0; mi < 4; ++mi)
#pragma unroll
      for (int ni = 0; ni < 4; ++ni)
        acc[mi][ni] = __builtin_amdgcn_mfma_f32_16x16x32_bf16(af[mi], bfv[ni],
                                                              acc[mi][ni], 0, 0, 0);
    cur ^= 1;
  }
  // epilogue
#pragma unroll
  for (int mi = 0; mi < 4; ++mi) {
#pragma unroll
    for (int ni = 0; ni < 4; ++ni) {
      int colg = n0 + wn + ni * 16 + (lane & 15);
      float bv = bias[colg];
#pragma unroll
      for (int rr = 0; rr < 4; ++rr) {
        int rowg = m0 + wm + mi * 16 + ((lane >> 4) << 2) + rr;
        float v = acc[mi][ni][rr] + bv;
        if (MODE == 1) {
          Cf[(size_t)rowg * N + colg] = v;
        } else {
          u16 b = f2bf(v);
          if (colg < D_MODEL) {
            int hh = colg >> 6, dd = colg & 63;
            Qd[((size_t)hh * S_LEN + rowg) * 64 + swz(rowg, dd)] = b;
          } else if (colg < 2 * D_MODEL) {
            int cc = colg - D_MODEL;
            int hh = cc >> 6, dd = cc & 63;
            Kd[((size_t)hh * S_LEN + rowg) * 64 + swz(rowg, dd)] = b;
          } else {
            int cc = colg - 2 * D_MODEL;
            int hh = cc >> 6, dd = cc & 63;
            int sl = rowg & 63;
            Vtd[((size_t)hh * 64 + dd) * S_LEN + (rowg & ~63) + swz(dd, sl)] = b;
          }
        }
      }
    }
  }
}

// ---------------- flash attention (causal), 128 Q-rows/block ----------------
__global__ __launch_bounds__(256) void k_flash(const u16* __restrict__ Qd,
                                               const u16* __restrict__ Kd,
                                               const u16* __restrict__ Vtd,
                                               u16* __restrict__ Ao) {
  __shared__ __align__(16) u16 Qs[128 * 64];
  __shared__ __align__(16) u16 Ks[64 * 64];
  __shared__ __align__(16) u16 Vs[64 * 64];
  __shared__ __align__(16) u16 Ps[4][32 * 64];
  const int tid = threadIdx.x, w = tid >> 6, lane = tid & 63;
  const int qt = blockIdx.x, h = blockIdx.y;
  const u16* Qh = Qd + (size_t)h * S_LEN * 64;
  const u16* Kh = Kd + (size_t)h * S_LEN * 64;
  const u16* Vh = Vtd + (size_t)h * 64 * S_LEN;
  const int r8 = tid >> 3, c8 = (tid & 7) * 8;

  {  // load Q tile [128][64] (globally pre-swizzled -> LDS holds swizzled rows)
    const u16* gq = Qh + ((size_t)(qt * 128 + r8)) * 64 + c8;
#pragma unroll
    for (int i = 0; i < 4; ++i) gload16(gq + (size_t)i * 32 * 64, Qs + i * 2048 + w * 512);
  }

  float m_run[2][4], l_run[2][4];
  f32x4 oacc[2][4] = {};
#pragma unroll
  for (int mi = 0; mi < 2; ++mi)
#pragma unroll
    for (int rr = 0; rr < 4; ++rr) {
      m_run[mi][rr] = -1e30f;
      l_run[mi][rr] = 0.f;
    }

  const int nkv = 2 * qt + 2;
  const float scale = 0.125f;

  for (int kv = 0; kv < nkv; ++kv) {
    __syncthreads();
    {
      const u16* gk = Kh + ((size_t)(kv * 64 + r8)) * 64 + c8;
      gload16(gk, Ks + w * 512);
      gload16(gk + 32 * 64, Ks + 2048 + w * 512);
      const u16* gv = Vh + (size_t)r8 * S_LEN + kv * 64 + c8;
      gload16(gv, Vs + w * 512);
      gload16(gv + (size_t)32 * S_LEN, Vs + 2048 + w * 512);
    }
    __syncthreads();

    // S = Q K^T
    f32x4 sacc[2][4] = {};
#pragma unroll
    for (int kk = 0; kk < 2; ++kk) {
      bf16x8 qa[2], kb[4];
#pragma unroll
      for (int mi = 0; mi < 2; ++mi) {
        int rq = w * 32 + mi * 16 + (lane & 15);
        qa[mi] = *reinterpret_cast<const bf16x8*>(
            Qs + rq * 64 + swz(rq, kk * 32 + (lane >> 4) * 8));
      }
#pragma unroll
      for (int ni = 0; ni < 4; ++ni) {
        int kvl = ni * 16 + (lane & 15);
        kb[ni] = *reinterpret_cast<const bf16x8*>(
            Ks + kvl * 64 + swz(kvl, kk * 32 + (lane >> 4) * 8));
      }
#pragma unroll
      for (int mi = 0; mi < 2; ++mi)
#pragma unroll
        for (int ni = 0; ni < 4; ++ni)
          sacc[mi][ni] = __builtin_amdgcn_mfma_f32_16x16x32_bf16(qa[mi], kb[ni],
                                                                 sacc[mi][ni], 0, 0, 0);
    }

    // mask + online softmax + P
#pragma unroll
    for (int mi = 0; mi < 2; ++mi) {
      int rowbase = qt * 128 + w * 32 + mi * 16 + ((lane >> 4) << 2);
      float pv[4][4];
#pragma unroll
      for (int ni = 0; ni < 4; ++ni) {
        int col = kv * 64 + ni * 16 + (lane & 15);
#pragma unroll
        for (int rr = 0; rr < 4; ++rr) {
          float sv = sacc[mi][ni][rr] * scale;
          pv[ni][rr] = (col > rowbase + rr) ? -1e30f : sv;
        }
      }
#pragma unroll
      for (int rr = 0; rr < 4; ++rr) {
        float mx = fmaxf(fmaxf(pv[0][rr], pv[1][rr]), fmaxf(pv[2][rr], pv[3][rr]));
#pragma unroll
        for (int d = 1; d < 16; d <<= 1) mx = fmaxf(mx, __shfl_xor(mx, d));
        float mn = fmaxf(m_run[mi][rr], mx);
        float alpha = __expf(m_run[mi][rr] - mn);
        m_run[mi][rr] = mn;
        float rs = 0.f;
#pragma unroll
        for (int ni = 0; ni < 4; ++ni) {
          float p = __expf(pv[ni][rr] - mn);
          pv[ni][rr] = p;
          rs += p;
        }
#pragma unroll
        for (int d = 1; d < 16; d <<= 1) rs += __shfl_xor(rs, d);
        l_run[mi][rr] = l_run[mi][rr] * alpha + rs;
#pragma unroll
        for (int ni = 0; ni < 4; ++ni) oacc[mi][ni][rr] *= alpha;
      }
#pragma unroll
      for (int ni = 0; ni < 4; ++ni)
#pragma unroll
        for (int rr = 0; rr < 4; ++rr) {
          int rowl = mi * 16 + ((lane >> 4) << 2) + rr;
          int coll = ni * 16 + (lane & 15);
          Ps[w][rowl * 64 + swz(rowl, coll)] = f2bf(pv[ni][rr]);
        }
    }

    // O += P V
#pragma unroll
    for (int kk = 0; kk < 2; ++kk) {
      bf16x8 pa[2], vb[4];
#pragma unroll
      for (int mi = 0; mi < 2; ++mi) {
        int pr = mi * 16 + (lane & 15);
        pa[mi] = *reinterpret_cast<const bf16x8*>(
            Ps[w] + pr * 64 + swz(pr, kk * 32 + (lane >> 4) * 8));
      }
#pragma unroll
      for (int ni = 0; ni < 4; ++ni) {
        int dd = ni * 16 + (lane & 15);
        vb[ni] = *reinterpret_cast<const bf16x8*>(
            Vs + dd * 64 + swz(dd, kk * 32 + (lane >> 4) * 8));
      }
#pragma unroll
      for (int mi = 0; mi < 2; ++mi)
#pragma unroll
        for (int ni = 0; ni < 4; ++ni)
          oacc[mi][ni] = __builtin_amdgcn_mfma_f32_16x16x32_bf16(pa[mi], vb[ni],
                                                                 oacc[mi][ni], 0, 0, 0);
    }
  }

  // write attention output, merged-head layout [S][1024] bf16
#pragma unroll
  for (int mi = 0; mi < 2; ++mi)
#pragma unroll
    for (int rr = 0; rr < 4; ++rr) {
      float inv = 1.f / l_run[mi][rr];
      int rowg = qt * 128 + w * 32 + mi * 16 + ((lane >> 4) << 2) + rr;
#pragma unroll
      for (int ni = 0; ni < 4; ++ni) {
        int colg = h * 64 + ni * 16 + (lane & 15);
        Ao[(size_t)rowg * D_MODEL + colg] = f2bf(oacc[mi][ni][rr] * inv);
      }
    }
}

extern "C" void kernel_launch(void* const* d_in, const int* in_sizes, int n_in,
                              void* d_out, int out_size, void* d_ws, size_t ws_size,
                              hipStream_t stream) {
  const float* x = (const float*)d_in[0];
  const float* Wqkv = (const float*)d_in[1];
  const float* bqkv = (const float*)d_in[2];
  const float* Wproj = (const float*)d_in[3];
  const float* bproj = (const float*)d_in[4];
  float* out = (float*)d_out;
  char* ws = (char*)d_ws;

  // Workspace map (40 MB total; aout aliases xb, which is dead after k_gemm<0>):
  u16* xb = (u16*)(ws);                            // [0,8) MB   x as bf16
  u16* aout = (u16*)(ws);                          // [0,8) MB   attn out (reuses xb)
  u16* wqkvt = (u16*)(ws + (size_t)(8 << 20));     // [8,14) MB  Wqkv^T bf16
  u16* wprojt = (u16*)(ws + (size_t)(14 << 20));   // [14,16) MB Wproj^T bf16
  u16* Qd = (u16*)(ws + (size_t)(16 << 20));       // [16,24) MB
  u16* Kd = (u16*)(ws + (size_t)(24 << 20));       // [24,32) MB
  u16* Vtd = (u16*)(ws + (size_t)(32 << 20));      // [32,40) MB

  if (ws_size < (size_t)(40 << 20)) return;  // refuse to scribble OOB

  k_conv<<<dim3(4096), dim3(256), 0, stream>>>(x, xb, S_LEN * D_MODEL);
  k_transpose_conv<<<dim3(96, 32), dim3(32, 8), 0, stream>>>(Wqkv, wqkvt, D_MODEL,
                                                             3 * D_MODEL);
  k_transpose_conv<<<dim3(32, 32), dim3(32, 8), 0, stream>>>(Wproj, wprojt, D_MODEL,
                                                             D_MODEL);
  k_gemm<0><<<dim3(24, 32), dim3(256), 0, stream>>>(xb, wqkvt, bqkv, nullptr, Qd, Kd,
                                                    Vtd, S_LEN, 3 * D_MODEL, D_MODEL);
  k_flash<<<dim3(32, 16), dim3(256), 0, stream>>>(Qd, Kd, Vtd, aout);
  k_gemm<1><<<dim3(8, 32), dim3(256), 0, stream>>>(aout, wprojt, bproj, out, nullptr,
                                                   nullptr, nullptr, S_LEN, D_MODEL,
                                                   D_MODEL);
}

// Round 5
// 272.751 us; speedup vs baseline: 1.3876x; 1.3876x over previous
//
#include <hip/hip_runtime.h>
#include <stdint.h>

typedef unsigned short u16;
typedef __bf16 bf16x8 __attribute__((ext_vector_type(8)));
typedef float f32x4 __attribute__((ext_vector_type(4)));

#define S_LEN 4096
#define D_MODEL 1024
#define NHEAD 16
#define HDIM 64

__device__ __forceinline__ u16 f2bf(float f) {
  unsigned u = __builtin_bit_cast(unsigned, f);
  u += 0x7fffu + ((u >> 16) & 1u);
  return (u16)(u >> 16);
}

// XOR swizzle of 16B units within a 128B (64 x bf16) row: unit ^= row&7
__device__ __forceinline__ int swz(int row, int col) {
  return (((col >> 3) ^ (row & 7)) << 3) | (col & 7);
}

__device__ __forceinline__ void gload16(const void* g, void* l) {
  auto gp = reinterpret_cast<__attribute__((address_space(1))) void*>(
      reinterpret_cast<uintptr_t>(g));
  auto lp = reinterpret_cast<__attribute__((address_space(3))) void*>(
      static_cast<unsigned>(reinterpret_cast<uintptr_t>(l)));
  __builtin_amdgcn_global_load_lds(gp, lp, 16, 0, 0);
}

// ---------------- fp32 -> bf16 elementwise ----------------
__global__ __launch_bounds__(256) void k_conv(const float* __restrict__ in,
                                              u16* __restrict__ out, int n) {
  int i = (blockIdx.x * 256 + threadIdx.x) * 4;
  if (i >= n) return;
  float4 v = *reinterpret_cast<const float4*>(in + i);
  ushort4 o = make_ushort4(f2bf(v.x), f2bf(v.y), f2bf(v.z), f2bf(v.w));
  *reinterpret_cast<ushort4*>(out + i) = o;
}

// ---------------- fp32 [R][C] -> bf16 [C][R] ----------------
__global__ __launch_bounds__(256) void k_transpose_conv(const float* __restrict__ in,
                                                        u16* __restrict__ out,
                                                        int R, int C) {
  __shared__ float tile[32][33];
  int c0 = blockIdx.x * 32, r0 = blockIdx.y * 32;
  int tx = threadIdx.x, ty = threadIdx.y;
#pragma unroll
  for (int j = 0; j < 4; ++j)
    tile[ty + j * 8][tx] = in[(size_t)(r0 + ty + j * 8) * C + c0 + tx];
  __syncthreads();
#pragma unroll
  for (int j = 0; j < 4; ++j)
    out[(size_t)(c0 + ty + j * 8) * R + r0 + tx] = f2bf(tile[tx][ty + j * 8]);
}

// ---------------- bf16 GEMM: C[M,N] = A[M,K] * Bt[N,K]^T + bias ----------------
// MODE 0: scatter into Q/K/Vt per-head bf16 layouts (with XOR swizzle)
// MODE 1: fp32 output, row-major
template <int MODE>
__global__ __launch_bounds__(256) void k_gemm(
    const u16* __restrict__ A, const u16* __restrict__ Bt,
    const float* __restrict__ bias, float* __restrict__ Cf,
    u16* __restrict__ Qd, u16* __restrict__ Kd, u16* __restrict__ Vtd,
    int M, int N, int K) {
  __shared__ __align__(16) u16 lds[2][2 * 128 * 32];
  const int tid = threadIdx.x;
  const int w = tid >> 6, lane = tid & 63;
  const int m0 = blockIdx.y * 128, n0 = blockIdx.x * 128;
  const u16* Atile = A + (size_t)m0 * K;
  const u16* Btile = Bt + (size_t)n0 * K;
  const int r = tid >> 2, c = (tid & 3) * 8;
  const int wm = (w >> 1) * 64, wn = (w & 1) * 64;

  f32x4 acc[4][4] = {};
  const int NT = K / 32;

  {  // stage tile 0
    const u16* ga = Atile + (size_t)r * K + c;
    const u16* gb = Btile + (size_t)r * K + c;
    u16* lb = lds[0];
    gload16(ga, lb + w * 512);
    gload16(ga + (size_t)64 * K, lb + 2048 + w * 512);
    gload16(gb, lb + 4096 + w * 512);
    gload16(gb + (size_t)64 * K, lb + 4096 + 2048 + w * 512);
  }
  int cur = 0;
  for (int t = 0; t < NT; ++t) {
    __syncthreads();
    if (t + 1 < NT) {
      const u16* ga = Atile + (size_t)r * K + (t + 1) * 32 + c;
      const u16* gb = Btile + (size_t)r * K + (t + 1) * 32 + c;
      u16* lb = lds[cur ^ 1];
      gload16(ga, lb + w * 512);
      gload16(ga + (size_t)64 * K, lb + 2048 + w * 512);
      gload16(gb, lb + 4096 + w * 512);
      gload16(gb + (size_t)64 * K, lb + 4096 + 2048 + w * 512);
    }
    const u16* lA = lds[cur];
    const u16* lB = lds[cur] + 4096;
    bf16x8 af[4], bfv[4];
#pragma unroll
    for (int mi = 0; mi < 4; ++mi)
      af[mi] = *reinterpret_cast<const bf16x8*>(
          lA + (wm + mi * 16 + (lane & 15)) * 32 + (lane >> 4) * 8);
#pragma unroll
    for (int ni = 0; ni < 4; ++ni)
      bfv[ni] = *reinterpret_cast<const bf16x8*>(
          lB + (wn + ni * 16 + (lane & 15)) * 32 + (lane >> 4) * 8);
#pragma unroll
    for (int mi = 0; mi < 4; ++mi)
#pragma unroll
      for (int ni = 0; ni < 4; ++ni)
        acc[mi][ni] = __builtin_amdgcn_mfma_f32_16x16x32_bf16(af[mi], bfv[ni],
                                                              acc[mi][ni], 0, 0, 0);
    cur ^= 1;
  }
  // epilogue
#pragma unroll
  for (int mi = 0; mi < 4; ++mi) {
#pragma unroll
    for (int ni = 0; ni < 4; ++ni) {
      int colg = n0 + wn + ni * 16 + (lane & 15);
      float bv = bias[colg];
#pragma unroll
      for (int rr = 0; rr < 4; ++rr) {
        int rowg = m0 + wm + mi * 16 + ((lane >> 4) << 2) + rr;
        float v = acc[mi][ni][rr] + bv;
        if (MODE == 1) {
          Cf[(size_t)rowg * N + colg] = v;
        } else {
          u16 b = f2bf(v);
          if (colg < D_MODEL) {
            int hh = colg >> 6, dd = colg & 63;
            Qd[((size_t)hh * S_LEN + rowg) * 64 + swz(rowg, dd)] = b;
          } else if (colg < 2 * D_MODEL) {
            int cc = colg - D_MODEL;
            int hh = cc >> 6, dd = cc & 63;
            Kd[((size_t)hh * S_LEN + rowg) * 64 + swz(rowg, dd)] = b;
          } else {
            int cc = colg - 2 * D_MODEL;
            int hh = cc >> 6, dd = cc & 63;
            int sl = rowg & 63;
            Vtd[((size_t)hh * 64 + dd) * S_LEN + (rowg & ~63) + swz(dd, sl)] = b;
          }
        }
      }
    }
  }
}

// ---------------- flash attention (causal), paired 64-row Q tiles ----------------
// Block handles qt = pid and qt = 63-pid  ->  65 +/- 1 KV iterations per block
// (perfect balance). K/V double-buffered, staged with issue-early gload_lds.
__global__ __launch_bounds__(256) void k_flash(const u16* __restrict__ Qd,
                                               const u16* __restrict__ Kd,
                                               const u16* __restrict__ Vtd,
                                               u16* __restrict__ Ao) {
  __shared__ __align__(16) u16 Qs[64 * 64];
  __shared__ __align__(16) u16 Ks[2][64 * 64];
  __shared__ __align__(16) u16 Vs[2][64 * 64];
  __shared__ __align__(16) u16 Ps[4][16 * 64];
  const int tid = threadIdx.x, w = tid >> 6, lane = tid & 63;
  const int pid = blockIdx.x, h = blockIdx.y;
  const u16* Qh = Qd + (size_t)h * S_LEN * 64;
  const u16* Kh = Kd + (size_t)h * S_LEN * 64;
  const u16* Vh = Vtd + (size_t)h * 64 * S_LEN;
  const int r8 = tid >> 3, c8 = (tid & 7) * 8;
  const float scale = 0.125f;

  int cur = 0;
  for (int rep = 0; rep < 2; ++rep) {
    const int qt = rep ? (63 - pid) : pid;

    {  // prologue: stage Q tile + K/V tile 0
      const u16* gq = Qh + ((size_t)(qt * 64 + r8)) * 64 + c8;
      gload16(gq, Qs + w * 512);
      gload16(gq + 32 * 64, Qs + 2048 + w * 512);
      const u16* gk = Kh + (size_t)r8 * 64 + c8;
      gload16(gk, Ks[cur] + w * 512);
      gload16(gk + 32 * 64, Ks[cur] + 2048 + w * 512);
      const u16* gv = Vh + (size_t)r8 * S_LEN + c8;
      gload16(gv, Vs[cur] + w * 512);
      gload16(gv + (size_t)32 * S_LEN, Vs[cur] + 2048 + w * 512);
    }
    __syncthreads();

    float m_run[4], l_run[4];
    f32x4 oacc[4] = {};
#pragma unroll
    for (int rr = 0; rr < 4; ++rr) {
      m_run[rr] = -1e30f;
      l_run[rr] = 0.f;
    }

    for (int j = 0; j <= qt; ++j) {
      // issue next tile's staging BEFORE compute (latency hides under compute)
      if (j < qt) {
        const u16* gk = Kh + ((size_t)((j + 1) * 64 + r8)) * 64 + c8;
        gload16(gk, Ks[cur ^ 1] + w * 512);
        gload16(gk + 32 * 64, Ks[cur ^ 1] + 2048 + w * 512);
        const u16* gv = Vh + (size_t)r8 * S_LEN + (j + 1) * 64 + c8;
        gload16(gv, Vs[cur ^ 1] + w * 512);
        gload16(gv + (size_t)32 * S_LEN, Vs[cur ^ 1] + 2048 + w * 512);
      }

      // S = Q K^T   (wave w owns Q rows [w*16, w*16+16))
      f32x4 sacc[4] = {};
#pragma unroll
      for (int kk = 0; kk < 2; ++kk) {
        const int rq = w * 16 + (lane & 15);
        bf16x8 qa = *reinterpret_cast<const bf16x8*>(
            Qs + rq * 64 + swz(rq, kk * 32 + (lane >> 4) * 8));
#pragma unroll
        for (int ni = 0; ni < 4; ++ni) {
          const int kvl = ni * 16 + (lane & 15);
          bf16x8 kb = *reinterpret_cast<const bf16x8*>(
              Ks[cur] + kvl * 64 + swz(kvl, kk * 32 + (lane >> 4) * 8));
          sacc[ni] = __builtin_amdgcn_mfma_f32_16x16x32_bf16(qa, kb, sacc[ni], 0, 0, 0);
        }
      }

      float pvv[4][4];
#pragma unroll
      for (int ni = 0; ni < 4; ++ni)
#pragma unroll
        for (int rr = 0; rr < 4; ++rr) pvv[ni][rr] = sacc[ni][rr] * scale;

      if (j == qt) {  // diagonal tile: causal mask (wave-uniform branch)
        const int rowb = qt * 64 + w * 16 + ((lane >> 4) << 2);
#pragma unroll
        for (int ni = 0; ni < 4; ++ni) {
          const int col = j * 64 + ni * 16 + (lane & 15);
#pragma unroll
          for (int rr = 0; rr < 4; ++rr)
            if (col > rowb + rr) pvv[ni][rr] = -1e30f;
        }
      }

      // online softmax (row spread over 16 lanes of same lane>>4 group)
#pragma unroll
      for (int rr = 0; rr < 4; ++rr) {
        float mx = fmaxf(fmaxf(pvv[0][rr], pvv[1][rr]), fmaxf(pvv[2][rr], pvv[3][rr]));
#pragma unroll
        for (int d = 1; d < 16; d <<= 1) mx = fmaxf(mx, __shfl_xor(mx, d));
        float mn = fmaxf(m_run[rr], mx);
        float alpha = __expf(m_run[rr] - mn);
        m_run[rr] = mn;
        float rs = 0.f;
#pragma unroll
        for (int ni = 0; ni < 4; ++ni) {
          float p = __expf(pvv[ni][rr] - mn);
          pvv[ni][rr] = p;
          rs += p;
        }
#pragma unroll
        for (int d = 1; d < 16; d <<= 1) rs += __shfl_xor(rs, d);
        l_run[rr] = l_run[rr] * alpha + rs;
#pragma unroll
        for (int ni = 0; ni < 4; ++ni) oacc[ni][rr] *= alpha;
      }

      // P -> LDS (per-wave private buffer; same-wave write->read, no barrier)
#pragma unroll
      for (int ni = 0; ni < 4; ++ni)
#pragma unroll
        for (int rr = 0; rr < 4; ++rr) {
          int rowl = ((lane >> 4) << 2) + rr;
          int coll = ni * 16 + (lane & 15);
          Ps[w][rowl * 64 + swz(rowl, coll)] = f2bf(pvv[ni][rr]);
        }

      // O += P V
#pragma unroll
      for (int kk = 0; kk < 2; ++kk) {
        const int pr = lane & 15;
        bf16x8 pa = *reinterpret_cast<const bf16x8*>(
            Ps[w] + pr * 64 + swz(pr, kk * 32 + (lane >> 4) * 8));
#pragma unroll
        for (int ni = 0; ni < 4; ++ni) {
          const int dd = ni * 16 + (lane & 15);
          bf16x8 vb = *reinterpret_cast<const bf16x8*>(
              Vs[cur] + dd * 64 + swz(dd, kk * 32 + (lane >> 4) * 8));
          oacc[ni] = __builtin_amdgcn_mfma_f32_16x16x32_bf16(pa, vb, oacc[ni], 0, 0, 0);
        }
      }

      __syncthreads();  // drains vmcnt (next tile landed) + all waves done with cur
      cur ^= 1;
    }

    // write attention output, merged-head layout [S][1024] bf16
#pragma unroll
    for (int rr = 0; rr < 4; ++rr) {
      float inv = 1.f / l_run[rr];
      int rowg = qt * 64 + w * 16 + ((lane >> 4) << 2) + rr;
#pragma unroll
      for (int ni = 0; ni < 4; ++ni) {
        int colg = h * 64 + ni * 16 + (lane & 15);
        Ao[(size_t)rowg * D_MODEL + colg] = f2bf(oacc[ni][rr] * inv);
      }
    }
  }
}

extern "C" void kernel_launch(void* const* d_in, const int* in_sizes, int n_in,
                              void* d_out, int out_size, void* d_ws, size_t ws_size,
                              hipStream_t stream) {
  const float* x = (const float*)d_in[0];
  const float* Wqkv = (const float*)d_in[1];
  const float* bqkv = (const float*)d_in[2];
  const float* Wproj = (const float*)d_in[3];
  const float* bproj = (const float*)d_in[4];
  float* out = (float*)d_out;
  char* ws = (char*)d_ws;

  // Workspace map (40 MB total; aout aliases xb, which is dead after k_gemm<0>):
  u16* xb = (u16*)(ws);                            // [0,8) MB   x as bf16
  u16* aout = (u16*)(ws);                          // [0,8) MB   attn out (reuses xb)
  u16* wqkvt = (u16*)(ws + (size_t)(8 << 20));     // [8,14) MB  Wqkv^T bf16
  u16* wprojt = (u16*)(ws + (size_t)(14 << 20));   // [14,16) MB Wproj^T bf16
  u16* Qd = (u16*)(ws + (size_t)(16 << 20));       // [16,24) MB
  u16* Kd = (u16*)(ws + (size_t)(24 << 20));       // [24,32) MB
  u16* Vtd = (u16*)(ws + (size_t)(32 << 20));      // [32,40) MB

  if (ws_size < (size_t)(40 << 20)) return;  // refuse to scribble OOB

  k_conv<<<dim3(4096), dim3(256), 0, stream>>>(x, xb, S_LEN * D_MODEL);
  k_transpose_conv<<<dim3(96, 32), dim3(32, 8), 0, stream>>>(Wqkv, wqkvt, D_MODEL,
                                                             3 * D_MODEL);
  k_transpose_conv<<<dim3(32, 32), dim3(32, 8), 0, stream>>>(Wproj, wprojt, D_MODEL,
                                                             D_MODEL);
  k_gemm<0><<<dim3(24, 32), dim3(256), 0, stream>>>(xb, wqkvt, bqkv, nullptr, Qd, Kd,
                                                    Vtd, S_LEN, 3 * D_MODEL, D_MODEL);
  k_flash<<<dim3(32, 16), dim3(256), 0, stream>>>(Qd, Kd, Vtd, aout);
  k_gemm<1><<<dim3(8, 32), dim3(256), 0, stream>>>(aout, wprojt, bproj, out, nullptr,
                                                   nullptr, nullptr, S_LEN, D_MODEL,
                                                   D_MODEL);
}